// Round 23
// baseline (307.036 us; speedup 1.0000x reference)
//
#include <hip/hip_runtime.h>

typedef float f4nt __attribute__((ext_vector_type(4)));   // NT-loadable float4

// ---------------- workspace layout (floats) ----------------
#define WS_XM    0                       // 512*100*64 = 3,276,800 (dead before fc1)
#define WS_FEAT  13107200                // 6,553,600
#define WS_PART  0                       // 64*512*256 = 8,388,608 (xm dead by then)
#define WS_S1    8388608                 // 25*512*256 = 3,276,800  [t][b][k]
#define WS_IN2   11665408                // 25*512*128 = 1,638,400
#define WS_S2    13303808                // 25*512*128 = 1,638,400 (FEAT dead by then)
#define WS_IN3   14942208                // 25*512*35  =   448,000
#define WS_WL    19660800                // 4608 folded conv2 weights [rem][c]
#define WS_SH2   (WS_WL + 4608)          // 32

// ---------------- prep: fold BN into conv2 weights, transposed [rem][c] ----------------
__global__ void prep_kernel(const float* __restrict__ w2, const float* __restrict__ cb2,
                            const float* __restrict__ g2, const float* __restrict__ bb2,
                            const float* __restrict__ m2, const float* __restrict__ v2,
                            float* __restrict__ wlg, float* __restrict__ sh2g) {
    const int tid = threadIdx.x;
    for (int i = tid; i < 4608; i += 256) {
        int c = i / 144, rem = i - c * 144;
        float inv = g2[c] * rsqrtf(v2[c] + 1e-5f);
        wlg[rem * 32 + c] = w2[i] * inv;
    }
    if (tid < 32) {
        float inv = g2[tid] * rsqrtf(v2[tid] + 1e-5f);
        sh2g[tid] = cb2[tid] * inv + bb2[tid] - m2[tid] * inv;
    }
}

// ---------------- mean: xm[b][h][w] = mean_t x[t][b][h][w] (pure streaming, high occ) ----------------
// 1600 blocks x 256 thr; each thread: 8 contiguous floats, 25 strided NT loads.
__global__ __launch_bounds__(256) void mean_kernel(const float* __restrict__ x,
                                                   float* __restrict__ xm) {
    const int i = blockIdx.x * 256 + threadIdx.x;    // 409,600 items of 8 floats
    const size_t o = (size_t)i * 8;
    const size_t TSTR = (size_t)512 * 6400;
    const float* px = x + o;
    f4nt a0 = {0.f, 0.f, 0.f, 0.f}, a1 = a0, c0 = a0, c1 = a0;
    #pragma unroll
    for (int tt = 0; tt < 24; tt += 2) {
        f4nt u0 = __builtin_nontemporal_load((const f4nt*)(px + (size_t)tt * TSTR));
        f4nt u1 = __builtin_nontemporal_load((const f4nt*)(px + (size_t)tt * TSTR + 4));
        f4nt u2 = __builtin_nontemporal_load((const f4nt*)(px + (size_t)(tt + 1) * TSTR));
        f4nt u3 = __builtin_nontemporal_load((const f4nt*)(px + (size_t)(tt + 1) * TSTR + 4));
        a0 += u0; a1 += u1; c0 += u2; c1 += u3;
    }
    f4nt u0 = __builtin_nontemporal_load((const f4nt*)(px + (size_t)24 * TSTR));
    f4nt u1 = __builtin_nontemporal_load((const f4nt*)(px + (size_t)24 * TSTR + 4));
    a0 += u0; a1 += u1;
    a0 += c0; a1 += c1;
    a0 *= (1.0f / 25.0f); a1 *= (1.0f / 25.0f);
    *(f4nt*)(xm + o)     = a0;
    *(f4nt*)(xm + o + 4) = a1;
}

// ---------------- FUSED conv1+conv2: xm -> (conv1,pool) in LDS -> conv2 -> feat ----------------
// grid (7, 512), 256 threads. Block covers pool2 rows s*4..s*4+3 of image b.
__global__ __launch_bounds__(256) void fused_conv_kernel(const float* __restrict__ xm,
                                                         const float* __restrict__ w1,
                                                         const float* __restrict__ cb1,
                                                         const float* __restrict__ g1,
                                                         const float* __restrict__ bb1,
                                                         const float* __restrict__ m1g,
                                                         const float* __restrict__ v1,
                                                         const float* __restrict__ wlg,
                                                         const float* __restrict__ sh2g,
                                                         float* __restrict__ feat) {
    __shared__ float xs[22 * 66];                       // 5,808 B
    __shared__ __align__(16) float p1L[10 * 16 * 36];   // 23,040 B
    __shared__ float w1s[144];
    __shared__ float sh1s[16];
    const int s = blockIdx.x, b = blockIdx.y;
    const int tid = threadIdx.x;

    if (tid < 144) {
        int c = tid / 9;
        float inv = g1[c] * rsqrtf(v1[c] + 1e-5f);
        w1s[tid] = w1[tid] * inv;
    }
    if (tid >= 144 && tid < 160) {
        int c = tid - 144;
        float inv = g1[c] * rsqrtf(v1[c] + 1e-5f);
        sh1s[c] = cb1[c] * inv + bb1[c] - m1g[c] * inv;
    }

    // ---- Phase A: load xm tile (rows 16s-3..16s+18, cols 0..63) into xs ----
    if (tid < 176) {
        int lr = tid >> 3, cq = tid & 7;
        int gxr = 16 * s - 3 + lr;
        f4nt a0 = {0.f, 0.f, 0.f, 0.f}, a1 = a0;
        if (gxr >= 0 && gxr < 100) {
            const float* px = xm + (size_t)b * 6400 + gxr * 64 + cq * 8;
            a0 = *(const f4nt*)px;
            a1 = *(const f4nt*)(px + 4);
        }
        float* d = &xs[lr * 66 + 1 + cq * 8];
        d[0] = a0.x; d[1] = a0.y; d[2] = a0.z; d[3] = a0.w;
        d[4] = a1.x; d[5] = a1.y; d[6] = a1.z; d[7] = a1.w;
    } else if (tid < 220) {
        int q = tid - 176;
        xs[(q >> 1) * 66 + (q & 1) * 65] = 0.f;          // cols -1 and 64
    }
    __syncthreads();

    // ---- Phase B: conv1 + pool -> p1L ----
    #pragma unroll 1
    for (int pos = tid; pos < 320; pos += 256) {
        int j = pos >> 5, pw = pos & 31;
        int gr = s * 8 - 1 + j;
        if (gr >= 0 && gr < 50) {
            float win[4][4];
            #pragma unroll
            for (int a = 0; a < 4; ++a)
                #pragma unroll
                for (int cc = 0; cc < 4; ++cc)
                    win[a][cc] = xs[(2 * j + a) * 66 + 2 * pw + cc];
            #pragma unroll 1
            for (int c = 0; c < 16; ++c) {
                float s00 = 0.f, s01 = 0.f, s10 = 0.f, s11 = 0.f;
                #pragma unroll
                for (int dh = 0; dh < 3; ++dh)
                    #pragma unroll
                    for (int dw = 0; dw < 3; ++dw) {
                        float w = w1s[c * 9 + dh * 3 + dw];
                        s00 = fmaf(win[dh][dw],         w, s00);
                        s01 = fmaf(win[dh][dw + 1],     w, s01);
                        s10 = fmaf(win[dh + 1][dw],     w, s10);
                        s11 = fmaf(win[dh + 1][dw + 1], w, s11);
                    }
                float m = fmaxf(fmaxf(s00, s01), fmaxf(s10, s11));
                p1L[(j * 16 + c) * 36 + 1 + pw] = fmaxf(m + sh1s[c], 0.f);
            }
        } else {
            #pragma unroll
            for (int c = 0; c < 16; ++c)
                p1L[(j * 16 + c) * 36 + 1 + pw] = 0.f;
        }
    }
    const int chg = tid & 15, q2 = (tid >> 4) & 3, phl = tid >> 6;
    const float* wbase = wlg + 2 * chg;
    float2 wcur[9], wnxt[9];
    #pragma unroll
    for (int t = 0; t < 9; ++t)
        wcur[t] = *(const float2*)&wbase[t * 32];
    for (int i = tid; i < 640; i += 256) {
        int rowi = i >> 2, col = i & 3;
        p1L[rowi * 36 + (col == 0 ? 0 : 32 + col)] = 0.f;
    }
    __syncthreads();

    // ---- Phase C: conv2 + pool -> feat ----
    const int ph = s * 4 + phl;
    const int xb = q2 * 8;
    float acc[2][2][8];
    #pragma unroll
    for (int c = 0; c < 2; ++c)
        #pragma unroll
        for (int a = 0; a < 2; ++a)
            #pragma unroll
            for (int xx = 0; xx < 8; ++xx) acc[c][a][xx] = 0.f;

    #pragma unroll 1
    for (int ci = 0; ci < 16; ++ci) {
        if (ci < 15) {
            #pragma unroll
            for (int t = 0; t < 9; ++t)
                wnxt[t] = *(const float2*)&wbase[((ci + 1) * 9 + t) * 32];
        }
        #pragma unroll
        for (int lr4 = 0; lr4 < 4; ++lr4) {
            const float* row = &p1L[((2 * phl + lr4) * 16 + ci) * 36 + xb];
            float v[10];
            float4 t0 = *(const float4*)&row[0];
            float4 t1 = *(const float4*)&row[4];
            float2 t2 = *(const float2*)&row[8];
            v[0]=t0.x; v[1]=t0.y; v[2]=t0.z; v[3]=t0.w;
            v[4]=t1.x; v[5]=t1.y; v[6]=t1.z; v[7]=t1.w;
            v[8]=t2.x; v[9]=t2.y;
            #pragma unroll
            for (int a = 0; a < 2; ++a) {
                const int dh = lr4 - a;
                if (dh >= 0 && dh <= 2) {
                    #pragma unroll
                    for (int dw = 0; dw < 3; ++dw) {
                        float w0 = wcur[dh * 3 + dw].x;
                        float w1 = wcur[dh * 3 + dw].y;
                        #pragma unroll
                        for (int xx = 0; xx < 8; ++xx) {
                            acc[0][a][xx] = fmaf(v[xx + dw], w0, acc[0][a][xx]);
                            acc[1][a][xx] = fmaf(v[xx + dw], w1, acc[1][a][xx]);
                        }
                    }
                }
            }
        }
        #pragma unroll
        for (int t = 0; t < 9; ++t) wcur[t] = wnxt[t];
    }
    if (ph < 25) {
        #pragma unroll
        for (int ch = 0; ch < 2; ++ch) {
            const int c = 2 * chg + ch;
            const float sh = sh2g[c];
            #pragma unroll
            for (int p = 0; p < 4; ++p) {
                float m = fmaxf(fmaxf(acc[ch][0][2 * p], acc[ch][0][2 * p + 1]),
                                fmaxf(acc[ch][1][2 * p], acc[ch][1][2 * p + 1]));
                float val = fmaxf(m + sh, 0.f);
                feat[(((size_t)b * 32 + c) * 25 + ph) * 16 + q2 * 4 + p] = val;
            }
        }
    }
}

// ---------------- fc1: split-K GEMM, 128x256 tile, 16x8 micro, BK=8, z=64 ----------------
__global__ __launch_bounds__(256, 1) void fc1_kernel(const float* __restrict__ feat,
                                                     const float* __restrict__ w,
                                                     float* __restrict__ part) {
    __shared__ float As[8 * 136];
    __shared__ float Bs[8 * 320];
    const int bx = blockIdx.x, bz = blockIdx.y;
    const int tid = threadIdx.x;
    const int tm = tid >> 5, tn = tid & 31;
    const int m0 = bx * 128;
    const int k0 = bz * 200;
    const int ar = tid >> 1, ac4 = (tid & 1) * 4;
    const int br = tid >> 1, bh = (tid & 1) * 4;
    const int gb0 = (br >> 3) * 10 + (br & 7);
    const int gb1 = ((br + 128) >> 3) * 10 + (br & 7);

    float acc[16][8] = {};
    float4 aP  = *(const float4*)(feat + (size_t)(m0 + ar) * 12800 + k0 + ac4);
    float4 bP0 = *(const float4*)(w + (size_t)br * 12800 + k0 + bh);
    float4 bP1 = *(const float4*)(w + (size_t)(br + 128) * 12800 + k0 + bh);

    for (int st = 0; st < 25; ++st) {
        __syncthreads();
        As[(ac4 + 0) * 136 + ar] = aP.x; As[(ac4 + 1) * 136 + ar] = aP.y;
        As[(ac4 + 2) * 136 + ar] = aP.z; As[(ac4 + 3) * 136 + ar] = aP.w;
        Bs[(bh + 0) * 320 + gb0] = bP0.x; Bs[(bh + 1) * 320 + gb0] = bP0.y;
        Bs[(bh + 2) * 320 + gb0] = bP0.z; Bs[(bh + 3) * 320 + gb0] = bP0.w;
        Bs[(bh + 0) * 320 + gb1] = bP1.x; Bs[(bh + 1) * 320 + gb1] = bP1.y;
        Bs[(bh + 2) * 320 + gb1] = bP1.z; Bs[(bh + 3) * 320 + gb1] = bP1.w;
        __syncthreads();
        if (st < 24) {
            const int o = k0 + (st + 1) * 8;
            aP  = *(const float4*)(feat + (size_t)(m0 + ar) * 12800 + o + ac4);
            bP0 = *(const float4*)(w + (size_t)br * 12800 + o + bh);
            bP1 = *(const float4*)(w + (size_t)(br + 128) * 12800 + o + bh);
        }
        #pragma unroll
        for (int kk = 0; kk < 8; ++kk) {
            float4 a0 = *(const float4*)&As[kk * 136 + tm * 16];
            float4 a1 = *(const float4*)&As[kk * 136 + tm * 16 + 4];
            float4 a2 = *(const float4*)&As[kk * 136 + tm * 16 + 8];
            float4 a3 = *(const float4*)&As[kk * 136 + tm * 16 + 12];
            float4 b0 = *(const float4*)&Bs[kk * 320 + tn * 10];
            float4 b1 = *(const float4*)&Bs[kk * 320 + tn * 10 + 4];
            float a_[16] = {a0.x, a0.y, a0.z, a0.w, a1.x, a1.y, a1.z, a1.w,
                            a2.x, a2.y, a2.z, a2.w, a3.x, a3.y, a3.z, a3.w};
            float b_[8]  = {b0.x, b0.y, b0.z, b0.w, b1.x, b1.y, b1.z, b1.w};
            #pragma unroll
            for (int i = 0; i < 16; ++i)
                #pragma unroll
                for (int j = 0; j < 8; ++j)
                    acc[i][j] = fmaf(a_[i], b_[j], acc[i][j]);
        }
    }
    #pragma unroll
    for (int i = 0; i < 16; ++i) {
        float* dst = &part[(size_t)bz * 131072 + (size_t)(m0 + tm * 16 + i) * 256 + tn * 8];
        *(float4*)dst       = make_float4(acc[i][0], acc[i][1], acc[i][2], acc[i][3]);
        *(float4*)(dst + 4) = make_float4(acc[i][4], acc[i][5], acc[i][6], acc[i][7]);
    }
}

// ---------------- lif1: reduce 64 fc1 partials + 25-step m1 scan -> S1 [t][b][k] ----------------
__global__ __launch_bounds__(256) void lif1_kernel(const float* __restrict__ part,
                                                   const float* __restrict__ b1g,
                                                   const float* __restrict__ pb1,
                                                   float* __restrict__ S1) {
    const int i = blockIdx.x * 256 + threadIdx.x;
    const int k = i & 255;
    float cu = b1g[k];
    #pragma unroll 8
    for (int z = 0; z < 64; ++z) cu += part[(size_t)z * 131072 + i];
    const float be = fminf(fmaxf(pb1[0], 0.f), 1.f);
    float m = 0.f;
    #pragma unroll
    for (int t = 0; t < 25; ++t) {
        float r = (m > 1.f) ? 1.f : 0.f;
        m = fmaf(be, m, cu) - r;
        S1[(size_t)t * 131072 + i] = (m > 1.f) ? 1.f : 0.f;
    }
}

// ---------------- fc2 GEMM: in2(12800,128) = S1 @ w2^T + b2, with prefetch ----------------
__global__ __launch_bounds__(256) void fc2g_kernel(const float* __restrict__ S1,
                                                   const float* __restrict__ w2g,
                                                   const float* __restrict__ b2g,
                                                   float* __restrict__ in2) {
    __shared__ float As[16 * 36];
    __shared__ float Bs[16 * 136];
    const int m0 = blockIdx.x * 32;
    const int tid = threadIdx.x;
    const int tm = tid >> 4, tn = tid & 15;
    const int ra = tid >> 2, cqa = tid & 3;
    const int rb = tid >> 1, kb = (tid & 1) * 8;
    float acc[2][8] = {};
    float4 av = make_float4(0.f, 0.f, 0.f, 0.f);
    if (tid < 128) av = *(const float4*)&S1[(size_t)(m0 + ra) * 256 + cqa * 4];
    float4 bv0 = *(const float4*)&w2g[rb * 256 + kb];
    float4 bv1 = *(const float4*)&w2g[rb * 256 + kb + 4];

    for (int kt = 0; kt < 16; ++kt) {
        __syncthreads();
        if (tid < 128) {
            As[(cqa * 4 + 0) * 36 + ra] = av.x; As[(cqa * 4 + 1) * 36 + ra] = av.y;
            As[(cqa * 4 + 2) * 36 + ra] = av.z; As[(cqa * 4 + 3) * 36 + ra] = av.w;
        }
        Bs[(kb + 0) * 136 + rb] = bv0.x; Bs[(kb + 1) * 136 + rb] = bv0.y;
        Bs[(kb + 2) * 136 + rb] = bv0.z; Bs[(kb + 3) * 136 + rb] = bv0.w;
        Bs[(kb + 4) * 136 + rb] = bv1.x; Bs[(kb + 5) * 136 + rb] = bv1.y;
        Bs[(kb + 6) * 136 + rb] = bv1.z; Bs[(kb + 7) * 136 + rb] = bv1.w;
        __syncthreads();
        if (kt < 15) {
            const int o = (kt + 1) * 16;
            if (tid < 128) av = *(const float4*)&S1[(size_t)(m0 + ra) * 256 + o + cqa * 4];
            bv0 = *(const float4*)&w2g[rb * 256 + o + kb];
            bv1 = *(const float4*)&w2g[rb * 256 + o + kb + 4];
        }
        #pragma unroll
        for (int kk = 0; kk < 16; ++kk) {
            float2 a2 = *(const float2*)&As[kk * 36 + tm * 2];
            float4 bw0 = *(const float4*)&Bs[kk * 136 + tn * 8];
            float4 bw1 = *(const float4*)&Bs[kk * 136 + tn * 8 + 4];
            float b_[8] = {bw0.x, bw0.y, bw0.z, bw0.w, bw1.x, bw1.y, bw1.z, bw1.w};
            #pragma unroll
            for (int j = 0; j < 8; ++j) {
                acc[0][j] = fmaf(a2.x, b_[j], acc[0][j]);
                acc[1][j] = fmaf(a2.y, b_[j], acc[1][j]);
            }
        }
    }
    float4 bb0 = *(const float4*)&b2g[tn * 8];
    float4 bb1 = *(const float4*)&b2g[tn * 8 + 4];
    #pragma unroll
    for (int i = 0; i < 2; ++i) {
        float* dst = &in2[(size_t)(m0 + tm * 2 + i) * 128 + tn * 8];
        *(float4*)dst       = make_float4(acc[i][0] + bb0.x, acc[i][1] + bb0.y,
                                          acc[i][2] + bb0.z, acc[i][3] + bb0.w);
        *(float4*)(dst + 4) = make_float4(acc[i][4] + bb1.x, acc[i][5] + bb1.y,
                                          acc[i][6] + bb1.z, acc[i][7] + bb1.w);
    }
}

// ---------------- lif2: 25-step m2 scan -> S2 ----------------
__global__ __launch_bounds__(256) void lif2_kernel(const float* __restrict__ in2,
                                                   const float* __restrict__ pb2,
                                                   float* __restrict__ S2) {
    const int i = blockIdx.x * 256 + threadIdx.x;
    const float be = fminf(fmaxf(pb2[0], 0.f), 1.f);
    float m = 0.f;
    #pragma unroll
    for (int t = 0; t < 25; ++t) {
        float r = (m > 1.f) ? 1.f : 0.f;
        m = fmaf(be, m, in2[(size_t)t * 65536 + i]) - r;
        S2[(size_t)t * 65536 + i] = (m > 1.f) ? 1.f : 0.f;
    }
}

// ---------------- fc3 GEMM ----------------
__global__ __launch_bounds__(256) void fc3g_kernel(const float* __restrict__ S2,
                                                   const float* __restrict__ w3g,
                                                   const float* __restrict__ b3g,
                                                   float* __restrict__ in3) {
    __shared__ float As[16 * 36];
    __shared__ float Bs[16 * 48];
    const int m0 = blockIdx.x * 32;
    const int tid = threadIdx.x;
    const int tm = tid >> 4, tn = tid & 15;
    float acc[2][3] = {};
    for (int kt = 0; kt < 8; ++kt) {
        __syncthreads();
        if (tid < 128) {
            int r = tid >> 2, cq = tid & 3;
            float4 av = *(const float4*)&S2[(size_t)(m0 + r) * 128 + kt * 16 + cq * 4];
            As[(cq * 4 + 0) * 36 + r] = av.x; As[(cq * 4 + 1) * 36 + r] = av.y;
            As[(cq * 4 + 2) * 36 + r] = av.z; As[(cq * 4 + 3) * 36 + r] = av.w;
        }
        for (int i = tid; i < 560; i += 256) {
            int kk = i / 35, c = i - kk * 35;
            Bs[kk * 48 + c] = w3g[c * 128 + kt * 16 + kk];
        }
        __syncthreads();
        #pragma unroll
        for (int kk = 0; kk < 16; ++kk) {
            float2 a2 = *(const float2*)&As[kk * 36 + tm * 2];
            float w0 = Bs[kk * 48 + tn];
            float w1 = Bs[kk * 48 + tn + 16];
            float w2 = Bs[kk * 48 + tn + 32];
            acc[0][0] = fmaf(a2.x, w0, acc[0][0]); acc[1][0] = fmaf(a2.y, w0, acc[1][0]);
            acc[0][1] = fmaf(a2.x, w1, acc[0][1]); acc[1][1] = fmaf(a2.y, w1, acc[1][1]);
            acc[0][2] = fmaf(a2.x, w2, acc[0][2]); acc[1][2] = fmaf(a2.y, w2, acc[1][2]);
        }
    }
    const float bias0 = b3g[tn];
    const float bias1 = b3g[tn + 16];
    const float bias2 = (tn < 3) ? b3g[tn + 32] : 0.f;
    #pragma unroll
    for (int i = 0; i < 2; ++i) {
        const size_t row = (size_t)(m0 + tm * 2 + i) * 35;
        in3[row + tn]      = acc[i][0] + bias0;
        in3[row + tn + 16] = acc[i][1] + bias1;
        if (tn < 3) in3[row + tn + 32] = acc[i][2] + bias2;
    }
}

// ---------------- lif3 ----------------
__global__ __launch_bounds__(256) void lif3_kernel(const float* __restrict__ in3,
                                                   const float* __restrict__ pb3,
                                                   float* __restrict__ out) {
    const int i = blockIdx.x * 256 + threadIdx.x;
    if (i >= 17920) return;
    const float be = fminf(fmaxf(pb3[0], 0.f), 1.f);
    float m = 0.f;
    #pragma unroll
    for (int t = 0; t < 25; ++t) {
        float r = (m > 1.f) ? 1.f : 0.f;
        m = fmaf(be, m, in3[(size_t)t * 17920 + i]) - r;
        out[(size_t)t * 17920 + i] = (m > 1.f) ? 1.f : 0.f;
    }
}

// ---------------- launch ----------------
extern "C" void kernel_launch(void* const* d_in, const int* in_sizes, int n_in,
                              void* d_out, int out_size, void* d_ws, size_t ws_size,
                              hipStream_t stream) {
    const float* x     = (const float*)d_in[0];
    const float* c1w   = (const float*)d_in[1];
    const float* c1b   = (const float*)d_in[2];
    const float* bn1g  = (const float*)d_in[3];
    const float* bn1b  = (const float*)d_in[4];
    const float* bn1m  = (const float*)d_in[5];
    const float* bn1v  = (const float*)d_in[6];
    const float* c2w   = (const float*)d_in[7];
    const float* c2b   = (const float*)d_in[8];
    const float* bn2g  = (const float*)d_in[9];
    const float* bn2b  = (const float*)d_in[10];
    const float* bn2m  = (const float*)d_in[11];
    const float* bn2v  = (const float*)d_in[12];
    const float* fc1w  = (const float*)d_in[13];
    const float* fc1b  = (const float*)d_in[14];
    const float* fc2w  = (const float*)d_in[15];
    const float* fc2b  = (const float*)d_in[16];
    const float* fc3w  = (const float*)d_in[17];
    const float* fc3b  = (const float*)d_in[18];
    const float* beta1 = (const float*)d_in[19];
    const float* beta2 = (const float*)d_in[20];
    const float* beta3 = (const float*)d_in[21];
    float* ws  = (float*)d_ws;
    float* out = (float*)d_out;

    prep_kernel<<<1, 256, 0, stream>>>(c2w, c2b, bn2g, bn2b, bn2m, bn2v,
                                       ws + WS_WL, ws + WS_SH2);
    mean_kernel<<<1600, 256, 0, stream>>>(x, ws + WS_XM);
    fused_conv_kernel<<<dim3(7, 512), 256, 0, stream>>>(ws + WS_XM, c1w, c1b, bn1g, bn1b,
                                                        bn1m, bn1v, ws + WS_WL, ws + WS_SH2,
                                                        ws + WS_FEAT);
    fc1_kernel<<<dim3(4, 64), 256, 0, stream>>>(ws + WS_FEAT, fc1w, ws + WS_PART);
    lif1_kernel<<<512, 256, 0, stream>>>(ws + WS_PART, fc1b, beta1, ws + WS_S1);
    fc2g_kernel<<<400, 256, 0, stream>>>(ws + WS_S1, fc2w, fc2b, ws + WS_IN2);
    lif2_kernel<<<256, 256, 0, stream>>>(ws + WS_IN2, beta2, ws + WS_S2);
    fc3g_kernel<<<400, 256, 0, stream>>>(ws + WS_S2, fc3w, fc3b, ws + WS_IN3);
    lif3_kernel<<<70, 256, 0, stream>>>(ws + WS_IN3, beta3, out);
}

// Round 24
// 281.445 us; speedup vs baseline: 1.0909x; 1.0909x over previous
//
#include <hip/hip_runtime.h>

typedef float f4nt __attribute__((ext_vector_type(4)));   // NT-loadable float4

// ---------------- workspace layout (floats) ----------------
#define WS_FEAT  13107200                // 6,553,600
#define WS_PART  0                       // 64*512*256 = 8,388,608
#define WS_S1    8388608                 // 25*512*256 = 3,276,800  [t][b][k]
#define WS_IN2   11665408                // 25*512*128 = 1,638,400
#define WS_S2    13303808                // 25*512*128 = 1,638,400 (FEAT dead by then)
#define WS_IN3   14942208                // 25*512*35  =   448,000
#define WS_WL    19660800                // 4608 folded conv2 weights [rem][c]
#define WS_SH2   (WS_WL + 4608)          // 32

// ---------------- prep: fold BN into conv2 weights, transposed [rem][c] ----------------
__global__ void prep_kernel(const float* __restrict__ w2, const float* __restrict__ cb2,
                            const float* __restrict__ g2, const float* __restrict__ bb2,
                            const float* __restrict__ m2, const float* __restrict__ v2,
                            float* __restrict__ wlg, float* __restrict__ sh2g) {
    const int tid = threadIdx.x;
    for (int i = tid; i < 4608; i += 256) {
        int c = i / 144, rem = i - c * 144;
        float inv = g2[c] * rsqrtf(v2[c] + 1e-5f);
        wlg[rem * 32 + c] = w2[i] * inv;
    }
    if (tid < 32) {
        float inv = g2[tid] * rsqrtf(v2[tid] + 1e-5f);
        sh2g[tid] = cb2[tid] * inv + bb2[tid] - m2[tid] * inv;
    }
}

// ---------------- FUSED conv1+conv2: x -> (mean,conv1,pool) in LDS -> conv2 -> feat ----------------
// grid (7, 512), 256 threads. Block covers pool2 rows s*4..s*4+3 of image b.
__global__ __launch_bounds__(256) void fused_conv_kernel(const float* __restrict__ x,
                                                         const float* __restrict__ w1,
                                                         const float* __restrict__ cb1,
                                                         const float* __restrict__ g1,
                                                         const float* __restrict__ bb1,
                                                         const float* __restrict__ m1g,
                                                         const float* __restrict__ v1,
                                                         const float* __restrict__ wlg,
                                                         const float* __restrict__ sh2g,
                                                         float* __restrict__ feat) {
    __shared__ float xs[22 * 66];                       // 5,808 B
    __shared__ __align__(16) float p1L[10 * 16 * 36];   // 23,040 B
    __shared__ float w1s[144];
    __shared__ float sh1s[16];
    const int s = blockIdx.x, b = blockIdx.y;
    const int tid = threadIdx.x;

    if (tid < 144) {
        int c = tid / 9;
        float inv = g1[c] * rsqrtf(v1[c] + 1e-5f);
        w1s[tid] = w1[tid] * inv;
    }
    if (tid >= 144 && tid < 160) {
        int c = tid - 144;
        float inv = g1[c] * rsqrtf(v1[c] + 1e-5f);
        sh1s[c] = cb1[c] * inv + bb1[c] - m1g[c] * inv;
    }

    // ---- Phase A: x-mean tile (176 items of 8 cols; 44 border zeros) ----
    const size_t TSTR = (size_t)512 * 6400;
    if (tid < 176) {
        int lr = tid >> 3, cq = tid & 7;
        int gxr = 16 * s - 3 + lr;
        f4nt a0 = {0.f, 0.f, 0.f, 0.f}, a1 = a0, c0 = a0, c1 = a0;
        if (gxr >= 0 && gxr < 100) {
            const float* px = x + (size_t)b * 6400 + gxr * 64 + cq * 8;
            #pragma unroll
            for (int tt = 0; tt < 24; tt += 2) {
                f4nt u0 = __builtin_nontemporal_load((const f4nt*)(px + (size_t)tt * TSTR));
                f4nt u1 = __builtin_nontemporal_load((const f4nt*)(px + (size_t)tt * TSTR + 4));
                f4nt u2 = __builtin_nontemporal_load((const f4nt*)(px + (size_t)(tt + 1) * TSTR));
                f4nt u3 = __builtin_nontemporal_load((const f4nt*)(px + (size_t)(tt + 1) * TSTR + 4));
                a0 += u0; a1 += u1; c0 += u2; c1 += u3;
            }
            f4nt u0 = __builtin_nontemporal_load((const f4nt*)(px + (size_t)24 * TSTR));
            f4nt u1 = __builtin_nontemporal_load((const f4nt*)(px + (size_t)24 * TSTR + 4));
            a0 += u0; a1 += u1;
            a0 += c0; a1 += c1;
            a0 *= (1.0f / 25.0f); a1 *= (1.0f / 25.0f);
        }
        float* d = &xs[lr * 66 + 1 + cq * 8];
        d[0] = a0.x; d[1] = a0.y; d[2] = a0.z; d[3] = a0.w;
        d[4] = a1.x; d[5] = a1.y; d[6] = a1.z; d[7] = a1.w;
    } else if (tid < 220) {
        int q = tid - 176;
        xs[(q >> 1) * 66 + (q & 1) * 65] = 0.f;          // cols -1 and 64
    }
    __syncthreads();

    // ---- Phase B: conv1 + pool -> p1L (320 positions; 16 channels each) ----
    #pragma unroll 1
    for (int pos = tid; pos < 320; pos += 256) {
        int j = pos >> 5, pw = pos & 31;
        int gr = s * 8 - 1 + j;                          // global p1 row
        if (gr >= 0 && gr < 50) {
            float win[4][4];
            #pragma unroll
            for (int a = 0; a < 4; ++a)
                #pragma unroll
                for (int cc = 0; cc < 4; ++cc)
                    win[a][cc] = xs[(2 * j + a) * 66 + 2 * pw + cc];
            #pragma unroll 1
            for (int c = 0; c < 16; ++c) {
                float s00 = 0.f, s01 = 0.f, s10 = 0.f, s11 = 0.f;
                #pragma unroll
                for (int dh = 0; dh < 3; ++dh)
                    #pragma unroll
                    for (int dw = 0; dw < 3; ++dw) {
                        float w = w1s[c * 9 + dh * 3 + dw];
                        s00 = fmaf(win[dh][dw],         w, s00);
                        s01 = fmaf(win[dh][dw + 1],     w, s01);
                        s10 = fmaf(win[dh + 1][dw],     w, s10);
                        s11 = fmaf(win[dh + 1][dw + 1], w, s11);
                    }
                float m = fmaxf(fmaxf(s00, s01), fmaxf(s10, s11));
                p1L[(j * 16 + c) * 36 + 1 + pw] = fmaxf(m + sh1s[c], 0.f);
            }
        } else {
            #pragma unroll
            for (int c = 0; c < 16; ++c)
                p1L[(j * 16 + c) * 36 + 1 + pw] = 0.f;
        }
    }
    // issue conv2 ci=0 weight loads (hide under border-zero + barrier)
    const int chg = tid & 15, q2 = (tid >> 4) & 3, phl = tid >> 6;
    const float* wbase = wlg + 2 * chg;
    float2 wcur[9], wnxt[9];
    #pragma unroll
    for (int t = 0; t < 9; ++t)
        wcur[t] = *(const float2*)&wbase[t * 32];
    // zero p1L border cols 0, 33, 34, 35 (640 items)
    for (int i = tid; i < 640; i += 256) {
        int rowi = i >> 2, col = i & 3;
        p1L[rowi * 36 + (col == 0 ? 0 : 32 + col)] = 0.f;
    }
    __syncthreads();

    // ---- Phase C: conv2 + pool -> feat ----
    const int ph = s * 4 + phl;
    const int xb = q2 * 8;
    float acc[2][2][8];
    #pragma unroll
    for (int c = 0; c < 2; ++c)
        #pragma unroll
        for (int a = 0; a < 2; ++a)
            #pragma unroll
            for (int xx = 0; xx < 8; ++xx) acc[c][a][xx] = 0.f;

    #pragma unroll 1
    for (int ci = 0; ci < 16; ++ci) {
        if (ci < 15) {
            #pragma unroll
            for (int t = 0; t < 9; ++t)
                wnxt[t] = *(const float2*)&wbase[((ci + 1) * 9 + t) * 32];
        }
        #pragma unroll
        for (int lr4 = 0; lr4 < 4; ++lr4) {
            const float* row = &p1L[((2 * phl + lr4) * 16 + ci) * 36 + xb];
            float v[10];
            float4 t0 = *(const float4*)&row[0];
            float4 t1 = *(const float4*)&row[4];
            float2 t2 = *(const float2*)&row[8];
            v[0]=t0.x; v[1]=t0.y; v[2]=t0.z; v[3]=t0.w;
            v[4]=t1.x; v[5]=t1.y; v[6]=t1.z; v[7]=t1.w;
            v[8]=t2.x; v[9]=t2.y;
            #pragma unroll
            for (int a = 0; a < 2; ++a) {
                const int dh = lr4 - a;
                if (dh >= 0 && dh <= 2) {
                    #pragma unroll
                    for (int dw = 0; dw < 3; ++dw) {
                        float w0 = wcur[dh * 3 + dw].x;
                        float w1 = wcur[dh * 3 + dw].y;
                        #pragma unroll
                        for (int xx = 0; xx < 8; ++xx) {
                            acc[0][a][xx] = fmaf(v[xx + dw], w0, acc[0][a][xx]);
                            acc[1][a][xx] = fmaf(v[xx + dw], w1, acc[1][a][xx]);
                        }
                    }
                }
            }
        }
        #pragma unroll
        for (int t = 0; t < 9; ++t) wcur[t] = wnxt[t];
    }
    if (ph < 25) {
        #pragma unroll
        for (int ch = 0; ch < 2; ++ch) {
            const int c = 2 * chg + ch;
            const float sh = sh2g[c];
            #pragma unroll
            for (int p = 0; p < 4; ++p) {
                float m = fmaxf(fmaxf(acc[ch][0][2 * p], acc[ch][0][2 * p + 1]),
                                fmaxf(acc[ch][1][2 * p], acc[ch][1][2 * p + 1]));
                float val = fmaxf(m + sh, 0.f);
                feat[(((size_t)b * 32 + c) * 25 + ph) * 16 + q2 * 4 + p] = val;
            }
        }
    }
}

// ---------------- fc1: split-K GEMM, 128x256 tile, 16x8 micro, BK=8, z=64 ----------------
__global__ __launch_bounds__(256, 1) void fc1_kernel(const float* __restrict__ feat,
                                                     const float* __restrict__ w,
                                                     float* __restrict__ part) {
    __shared__ float As[8 * 136];
    __shared__ float Bs[8 * 320];
    const int bx = blockIdx.x, bz = blockIdx.y;
    const int tid = threadIdx.x;
    const int tm = tid >> 5, tn = tid & 31;
    const int m0 = bx * 128;
    const int k0 = bz * 200;
    const int ar = tid >> 1, ac4 = (tid & 1) * 4;
    const int br = tid >> 1, bh = (tid & 1) * 4;
    const int gb0 = (br >> 3) * 10 + (br & 7);
    const int gb1 = ((br + 128) >> 3) * 10 + (br & 7);

    float acc[16][8] = {};
    float4 aP  = *(const float4*)(feat + (size_t)(m0 + ar) * 12800 + k0 + ac4);
    float4 bP0 = *(const float4*)(w + (size_t)br * 12800 + k0 + bh);
    float4 bP1 = *(const float4*)(w + (size_t)(br + 128) * 12800 + k0 + bh);

    for (int st = 0; st < 25; ++st) {
        __syncthreads();
        As[(ac4 + 0) * 136 + ar] = aP.x; As[(ac4 + 1) * 136 + ar] = aP.y;
        As[(ac4 + 2) * 136 + ar] = aP.z; As[(ac4 + 3) * 136 + ar] = aP.w;
        Bs[(bh + 0) * 320 + gb0] = bP0.x; Bs[(bh + 1) * 320 + gb0] = bP0.y;
        Bs[(bh + 2) * 320 + gb0] = bP0.z; Bs[(bh + 3) * 320 + gb0] = bP0.w;
        Bs[(bh + 0) * 320 + gb1] = bP1.x; Bs[(bh + 1) * 320 + gb1] = bP1.y;
        Bs[(bh + 2) * 320 + gb1] = bP1.z; Bs[(bh + 3) * 320 + gb1] = bP1.w;
        __syncthreads();
        if (st < 24) {
            const int o = k0 + (st + 1) * 8;
            aP  = *(const float4*)(feat + (size_t)(m0 + ar) * 12800 + o + ac4);
            bP0 = *(const float4*)(w + (size_t)br * 12800 + o + bh);
            bP1 = *(const float4*)(w + (size_t)(br + 128) * 12800 + o + bh);
        }
        #pragma unroll
        for (int kk = 0; kk < 8; ++kk) {
            float4 a0 = *(const float4*)&As[kk * 136 + tm * 16];
            float4 a1 = *(const float4*)&As[kk * 136 + tm * 16 + 4];
            float4 a2 = *(const float4*)&As[kk * 136 + tm * 16 + 8];
            float4 a3 = *(const float4*)&As[kk * 136 + tm * 16 + 12];
            float4 b0 = *(const float4*)&Bs[kk * 320 + tn * 10];
            float4 b1 = *(const float4*)&Bs[kk * 320 + tn * 10 + 4];
            float a_[16] = {a0.x, a0.y, a0.z, a0.w, a1.x, a1.y, a1.z, a1.w,
                            a2.x, a2.y, a2.z, a2.w, a3.x, a3.y, a3.z, a3.w};
            float b_[8]  = {b0.x, b0.y, b0.z, b0.w, b1.x, b1.y, b1.z, b1.w};
            #pragma unroll
            for (int i = 0; i < 16; ++i)
                #pragma unroll
                for (int j = 0; j < 8; ++j)
                    acc[i][j] = fmaf(a_[i], b_[j], acc[i][j]);
        }
    }
    #pragma unroll
    for (int i = 0; i < 16; ++i) {
        float* dst = &part[(size_t)bz * 131072 + (size_t)(m0 + tm * 16 + i) * 256 + tn * 8];
        *(float4*)dst       = make_float4(acc[i][0], acc[i][1], acc[i][2], acc[i][3]);
        *(float4*)(dst + 4) = make_float4(acc[i][4], acc[i][5], acc[i][6], acc[i][7]);
    }
}

// ---------------- lif1: reduce 64 fc1 partials + 25-step m1 scan -> S1 [t][b][k] ----------------
__global__ __launch_bounds__(256) void lif1_kernel(const float* __restrict__ part,
                                                   const float* __restrict__ b1g,
                                                   const float* __restrict__ pb1,
                                                   float* __restrict__ S1) {
    const int i = blockIdx.x * 256 + threadIdx.x;
    const int k = i & 255;
    float cu = b1g[k];
    #pragma unroll 8
    for (int z = 0; z < 64; ++z) cu += part[(size_t)z * 131072 + i];
    const float be = fminf(fmaxf(pb1[0], 0.f), 1.f);
    float m = 0.f;
    #pragma unroll
    for (int t = 0; t < 25; ++t) {
        float r = (m > 1.f) ? 1.f : 0.f;
        m = fmaf(be, m, cu) - r;
        S1[(size_t)t * 131072 + i] = (m > 1.f) ? 1.f : 0.f;
    }
}

// ---------------- fc2 GEMM: in2(12800,128) = S1 @ w2^T + b2, with prefetch ----------------
__global__ __launch_bounds__(256) void fc2g_kernel(const float* __restrict__ S1,
                                                   const float* __restrict__ w2g,
                                                   const float* __restrict__ b2g,
                                                   float* __restrict__ in2) {
    __shared__ float As[16 * 36];
    __shared__ float Bs[16 * 136];
    const int m0 = blockIdx.x * 32;
    const int tid = threadIdx.x;
    const int tm = tid >> 4, tn = tid & 15;
    const int ra = tid >> 2, cqa = tid & 3;
    const int rb = tid >> 1, kb = (tid & 1) * 8;
    float acc[2][8] = {};
    float4 av = make_float4(0.f, 0.f, 0.f, 0.f);
    if (tid < 128) av = *(const float4*)&S1[(size_t)(m0 + ra) * 256 + cqa * 4];
    float4 bv0 = *(const float4*)&w2g[rb * 256 + kb];
    float4 bv1 = *(const float4*)&w2g[rb * 256 + kb + 4];

    for (int kt = 0; kt < 16; ++kt) {
        __syncthreads();
        if (tid < 128) {
            As[(cqa * 4 + 0) * 36 + ra] = av.x; As[(cqa * 4 + 1) * 36 + ra] = av.y;
            As[(cqa * 4 + 2) * 36 + ra] = av.z; As[(cqa * 4 + 3) * 36 + ra] = av.w;
        }
        Bs[(kb + 0) * 136 + rb] = bv0.x; Bs[(kb + 1) * 136 + rb] = bv0.y;
        Bs[(kb + 2) * 136 + rb] = bv0.z; Bs[(kb + 3) * 136 + rb] = bv0.w;
        Bs[(kb + 4) * 136 + rb] = bv1.x; Bs[(kb + 5) * 136 + rb] = bv1.y;
        Bs[(kb + 6) * 136 + rb] = bv1.z; Bs[(kb + 7) * 136 + rb] = bv1.w;
        __syncthreads();
        if (kt < 15) {
            const int o = (kt + 1) * 16;
            if (tid < 128) av = *(const float4*)&S1[(size_t)(m0 + ra) * 256 + o + cqa * 4];
            bv0 = *(const float4*)&w2g[rb * 256 + o + kb];
            bv1 = *(const float4*)&w2g[rb * 256 + o + kb + 4];
        }
        #pragma unroll
        for (int kk = 0; kk < 16; ++kk) {
            float2 a2 = *(const float2*)&As[kk * 36 + tm * 2];
            float4 bw0 = *(const float4*)&Bs[kk * 136 + tn * 8];
            float4 bw1 = *(const float4*)&Bs[kk * 136 + tn * 8 + 4];
            float b_[8] = {bw0.x, bw0.y, bw0.z, bw0.w, bw1.x, bw1.y, bw1.z, bw1.w};
            #pragma unroll
            for (int j = 0; j < 8; ++j) {
                acc[0][j] = fmaf(a2.x, b_[j], acc[0][j]);
                acc[1][j] = fmaf(a2.y, b_[j], acc[1][j]);
            }
        }
    }
    float4 bb0 = *(const float4*)&b2g[tn * 8];
    float4 bb1 = *(const float4*)&b2g[tn * 8 + 4];
    #pragma unroll
    for (int i = 0; i < 2; ++i) {
        float* dst = &in2[(size_t)(m0 + tm * 2 + i) * 128 + tn * 8];
        *(float4*)dst       = make_float4(acc[i][0] + bb0.x, acc[i][1] + bb0.y,
                                          acc[i][2] + bb0.z, acc[i][3] + bb0.w);
        *(float4*)(dst + 4) = make_float4(acc[i][4] + bb1.x, acc[i][5] + bb1.y,
                                          acc[i][6] + bb1.z, acc[i][7] + bb1.w);
    }
}

// ---------------- lif2: 25-step m2 scan -> S2 ----------------
__global__ __launch_bounds__(256) void lif2_kernel(const float* __restrict__ in2,
                                                   const float* __restrict__ pb2,
                                                   float* __restrict__ S2) {
    const int i = blockIdx.x * 256 + threadIdx.x;
    const float be = fminf(fmaxf(pb2[0], 0.f), 1.f);
    float m = 0.f;
    #pragma unroll
    for (int t = 0; t < 25; ++t) {
        float r = (m > 1.f) ? 1.f : 0.f;
        m = fmaf(be, m, in2[(size_t)t * 65536 + i]) - r;
        S2[(size_t)t * 65536 + i] = (m > 1.f) ? 1.f : 0.f;
    }
}

// ---------------- fc3 GEMM ----------------
__global__ __launch_bounds__(256) void fc3g_kernel(const float* __restrict__ S2,
                                                   const float* __restrict__ w3g,
                                                   const float* __restrict__ b3g,
                                                   float* __restrict__ in3) {
    __shared__ float As[16 * 36];
    __shared__ float Bs[16 * 48];
    const int m0 = blockIdx.x * 32;
    const int tid = threadIdx.x;
    const int tm = tid >> 4, tn = tid & 15;
    float acc[2][3] = {};
    for (int kt = 0; kt < 8; ++kt) {
        __syncthreads();
        if (tid < 128) {
            int r = tid >> 2, cq = tid & 3;
            float4 av = *(const float4*)&S2[(size_t)(m0 + r) * 128 + kt * 16 + cq * 4];
            As[(cq * 4 + 0) * 36 + r] = av.x; As[(cq * 4 + 1) * 36 + r] = av.y;
            As[(cq * 4 + 2) * 36 + r] = av.z; As[(cq * 4 + 3) * 36 + r] = av.w;
        }
        for (int i = tid; i < 560; i += 256) {
            int kk = i / 35, c = i - kk * 35;
            Bs[kk * 48 + c] = w3g[c * 128 + kt * 16 + kk];
        }
        __syncthreads();
        #pragma unroll
        for (int kk = 0; kk < 16; ++kk) {
            float2 a2 = *(const float2*)&As[kk * 36 + tm * 2];
            float w0 = Bs[kk * 48 + tn];
            float w1 = Bs[kk * 48 + tn + 16];
            float w2 = Bs[kk * 48 + tn + 32];
            acc[0][0] = fmaf(a2.x, w0, acc[0][0]); acc[1][0] = fmaf(a2.y, w0, acc[1][0]);
            acc[0][1] = fmaf(a2.x, w1, acc[0][1]); acc[1][1] = fmaf(a2.y, w1, acc[1][1]);
            acc[0][2] = fmaf(a2.x, w2, acc[0][2]); acc[1][2] = fmaf(a2.y, w2, acc[1][2]);
        }
    }
    const float bias0 = b3g[tn];
    const float bias1 = b3g[tn + 16];
    const float bias2 = (tn < 3) ? b3g[tn + 32] : 0.f;
    #pragma unroll
    for (int i = 0; i < 2; ++i) {
        const size_t row = (size_t)(m0 + tm * 2 + i) * 35;
        in3[row + tn]      = acc[i][0] + bias0;
        in3[row + tn + 16] = acc[i][1] + bias1;
        if (tn < 3) in3[row + tn + 32] = acc[i][2] + bias2;
    }
}

// ---------------- lif3 ----------------
__global__ __launch_bounds__(256) void lif3_kernel(const float* __restrict__ in3,
                                                   const float* __restrict__ pb3,
                                                   float* __restrict__ out) {
    const int i = blockIdx.x * 256 + threadIdx.x;
    if (i >= 17920) return;
    const float be = fminf(fmaxf(pb3[0], 0.f), 1.f);
    float m = 0.f;
    #pragma unroll
    for (int t = 0; t < 25; ++t) {
        float r = (m > 1.f) ? 1.f : 0.f;
        m = fmaf(be, m, in3[(size_t)t * 17920 + i]) - r;
        out[(size_t)t * 17920 + i] = (m > 1.f) ? 1.f : 0.f;
    }
}

// ---------------- launch ----------------
extern "C" void kernel_launch(void* const* d_in, const int* in_sizes, int n_in,
                              void* d_out, int out_size, void* d_ws, size_t ws_size,
                              hipStream_t stream) {
    const float* x     = (const float*)d_in[0];
    const float* c1w   = (const float*)d_in[1];
    const float* c1b   = (const float*)d_in[2];
    const float* bn1g  = (const float*)d_in[3];
    const float* bn1b  = (const float*)d_in[4];
    const float* bn1m  = (const float*)d_in[5];
    const float* bn1v  = (const float*)d_in[6];
    const float* c2w   = (const float*)d_in[7];
    const float* c2b   = (const float*)d_in[8];
    const float* bn2g  = (const float*)d_in[9];
    const float* bn2b  = (const float*)d_in[10];
    const float* bn2m  = (const float*)d_in[11];
    const float* bn2v  = (const float*)d_in[12];
    const float* fc1w  = (const float*)d_in[13];
    const float* fc1b  = (const float*)d_in[14];
    const float* fc2w  = (const float*)d_in[15];
    const float* fc2b  = (const float*)d_in[16];
    const float* fc3w  = (const float*)d_in[17];
    const float* fc3b  = (const float*)d_in[18];
    const float* beta1 = (const float*)d_in[19];
    const float* beta2 = (const float*)d_in[20];
    const float* beta3 = (const float*)d_in[21];
    float* ws  = (float*)d_ws;
    float* out = (float*)d_out;

    prep_kernel<<<1, 256, 0, stream>>>(c2w, c2b, bn2g, bn2b, bn2m, bn2v,
                                       ws + WS_WL, ws + WS_SH2);
    fused_conv_kernel<<<dim3(7, 512), 256, 0, stream>>>(x, c1w, c1b, bn1g, bn1b, bn1m, bn1v,
                                                        ws + WS_WL, ws + WS_SH2, ws + WS_FEAT);
    fc1_kernel<<<dim3(4, 64), 256, 0, stream>>>(ws + WS_FEAT, fc1w, ws + WS_PART);
    lif1_kernel<<<512, 256, 0, stream>>>(ws + WS_PART, fc1b, beta1, ws + WS_S1);
    fc2g_kernel<<<400, 256, 0, stream>>>(ws + WS_S1, fc2w, fc2b, ws + WS_IN2);
    lif2_kernel<<<256, 256, 0, stream>>>(ws + WS_IN2, beta2, ws + WS_S2);
    fc3g_kernel<<<400, 256, 0, stream>>>(ws + WS_S2, fc3w, fc3b, ws + WS_IN3);
    lif3_kernel<<<70, 256, 0, stream>>>(ws + WS_IN3, beta3, out);
}